// Round 13
// baseline (175.116 us; speedup 1.0000x reference)
//
#include <hip/hip_runtime.h>

// x:     [B=16, C=64, H=256, W=256] float32
// w_off: [2, 64] float32
// b_off: [2] float32
// out:   [16, 64, 256, 256] float32
#define BB 16
#define CC 64
#define HH 256
#define WW 256
#define HW (HH * WW)

// ws layout: xt bf16 [B][H][W][C] (134 MB) then pq float2 (8 MB)
#define XT_BYTES 134217728ULL
#define NEED_WS  (XT_BYTES + 8388608ULL)

typedef float    fx4 __attribute__((ext_vector_type(4)));
typedef unsigned ux4 __attribute__((ext_vector_type(4)));

__device__ __forceinline__ unsigned f2bf(float f) {
    unsigned u = __float_as_uint(f);
    u += 0x7FFFu + ((u >> 16) & 1u);          // RNE
    return u >> 16;
}
__device__ __forceinline__ float bflo(unsigned w) { return __uint_as_float(w << 16); }
__device__ __forceinline__ float bfhi(unsigned w) { return __uint_as_float(w & 0xFFFF0000u); }

// ---------------- shared-body macros (verified R12 bodies) ----------------
#define PREP_BODY(B_, ROW_, PACK_, W0_, W1_)                                        \
    {                                                                               \
        if (t < CC)          W0_[t]      = w_off[t];                                \
        else if (t < 2*CC)   W1_[t - CC] = w_off[t];                                \
        __syncthreads();                                                            \
        const float* __restrict__ xb = x + (size_t)(B_) * CC * HW + (ROW_) * WW + t;\
        float a0 = 0.f, a1 = 0.f, vprev = 0.f;                                      \
        _Pragma("unroll 16")                                                        \
        for (int c = 0; c < CC; ++c) {                                              \
            const float v = xb[(size_t)c * HW];                                     \
            a0 = fmaf(v, W0_[c], a0);                                               \
            a1 = fmaf(v, W1_[c], a1);                                               \
            if (c & 1) PACK_[c >> 1][t] = f2bf(vprev) | (f2bf(v) << 16);            \
            vprev = v;                                                              \
        }                                                                           \
        const float offx = tanhf(a0 + b_off[0]) * 0.5f;                             \
        const float offy = tanhf(a1 + b_off[1]) * 0.5f;                             \
        const float gx = -1.0f + (float)t      * (2.0f / (WW - 1)) + offx;          \
        const float gy = -1.0f + (float)(ROW_) * (2.0f / (HH - 1)) + offy;          \
        pq[(size_t)(B_) * HW + (ROW_) * WW + t] =                                   \
            make_float2(((gx + 1.0f) * (float)WW - 1.0f) * 0.5f,                    \
                        ((gy + 1.0f) * (float)HH - 1.0f) * 0.5f);                   \
        __syncthreads();                                                            \
        const int j  = t & 7;                                                       \
        const int pb = t >> 3;                                                      \
        unsigned* __restrict__ xto = xt + ((size_t)(B_) * HW + (size_t)(ROW_) * WW) * 32; \
        _Pragma("unroll")                                                           \
        for (int g = 0; g < 8; ++g) {                                               \
            const int p = g * 32 + pb;                                              \
            ux4 v;                                                                  \
            v.x = PACK_[4 * j + 0][p];                                              \
            v.y = PACK_[4 * j + 1][p];                                              \
            v.z = PACK_[4 * j + 2][p];                                              \
            v.w = PACK_[4 * j + 3][p];                                              \
            *reinterpret_cast<ux4*>(xto + (size_t)p * 32 + j * 4) = v;              \
        }                                                                           \
    }

#define COORDS(prc, W00, W01, W10, W11, I00, I01, I10, I11)                         \
    {                                                                               \
        const float x0f = floorf(prc.x), y0f = floorf(prc.y);                       \
        const float wx1 = prc.x - x0f,  wy1 = prc.y - y0f;                          \
        const float wx0 = 1.f - wx1,   wy0 = 1.f - wy1;                             \
        const int x0 = (int)x0f, y0 = (int)y0f, x1 = x0 + 1, y1 = y0 + 1;           \
        const bool vx0 = (unsigned)x0 < WW, vx1 = (unsigned)x1 < WW;                \
        const bool vy0 = (unsigned)y0 < HH, vy1 = (unsigned)y1 < HH;                \
        const int cx0 = min(max(x0, 0), WW - 1), cx1 = min(max(x1, 0), WW - 1);     \
        const int cy0 = min(max(y0, 0), HH - 1), cy1 = min(max(y1, 0), HH - 1);     \
        W00 = (vx0 && vy0) ? wx0 * wy0 : 0.f;                                       \
        W01 = (vx1 && vy0) ? wx1 * wy0 : 0.f;                                       \
        W10 = (vx0 && vy1) ? wx0 * wy1 : 0.f;                                       \
        W11 = (vx1 && vy1) ? wx1 * wy1 : 0.f;                                       \
        I00 = (unsigned)(cy0 * WW + cx0) * 32u + l8 * 4u;                           \
        I01 = (unsigned)(cy0 * WW + cx1) * 32u + l8 * 4u;                           \
        I10 = (unsigned)(cy1 * WW + cx0) * 32u + l8 * 4u;                           \
        I11 = (unsigned)(cy1 * WW + cx1) * 32u + l8 * 4u;                           \
    }

#define BLEND_STORE(SO_, BUF, V00, V01, V10, V11, W00, W01, W10, W11, PXL)          \
    {                                                                               \
        float f0 = W00 * bflo(V00.x); float f1 = W00 * bfhi(V00.x);                 \
        float f2 = W00 * bflo(V00.y); float f3 = W00 * bfhi(V00.y);                 \
        float f4 = W00 * bflo(V00.z); float f5 = W00 * bfhi(V00.z);                 \
        float f6 = W00 * bflo(V00.w); float f7 = W00 * bfhi(V00.w);                 \
        f0 = fmaf(W01, bflo(V01.x), f0); f1 = fmaf(W01, bfhi(V01.x), f1);           \
        f2 = fmaf(W01, bflo(V01.y), f2); f3 = fmaf(W01, bfhi(V01.y), f3);           \
        f4 = fmaf(W01, bflo(V01.z), f4); f5 = fmaf(W01, bfhi(V01.z), f5);           \
        f6 = fmaf(W01, bflo(V01.w), f6); f7 = fmaf(W01, bfhi(V01.w), f7);           \
        f0 = fmaf(W10, bflo(V10.x), f0); f1 = fmaf(W10, bfhi(V10.x), f1);           \
        f2 = fmaf(W10, bflo(V10.y), f2); f3 = fmaf(W10, bfhi(V10.y), f3);           \
        f4 = fmaf(W10, bflo(V10.z), f4); f5 = fmaf(W10, bfhi(V10.z), f5);           \
        f6 = fmaf(W10, bflo(V10.w), f6); f7 = fmaf(W10, bfhi(V10.w), f7);           \
        f0 = fmaf(W11, bflo(V11.x), f0); f1 = fmaf(W11, bfhi(V11.x), f1);           \
        f2 = fmaf(W11, bflo(V11.y), f2); f3 = fmaf(W11, bfhi(V11.y), f3);           \
        f4 = fmaf(W11, bflo(V11.z), f4); f5 = fmaf(W11, bfhi(V11.z), f5);           \
        f6 = fmaf(W11, bflo(V11.w), f6); f7 = fmaf(W11, bfhi(V11.w), f7);           \
        SO_[BUF][c8 + 0][PXL] = f0; SO_[BUF][c8 + 1][PXL] = f1;                     \
        SO_[BUF][c8 + 2][PXL] = f2; SO_[BUF][c8 + 3][PXL] = f3;                     \
        SO_[BUF][c8 + 4][PXL] = f4; SO_[BUF][c8 + 5][PXL] = f5;                     \
        SO_[BUF][c8 + 6][PXL] = f6; SO_[BUF][c8 + 7][PXL] = f7;                     \
    }

#define WRITEOUT(SO_, BUF, B_, ROW_, PX0_, QOFF)                                    \
    {                                                                               \
        const int p  = t & 15;                                                      \
        const int cg = (t >> 4) & 3;                                                \
        const int wv = t >> 6;                                                      \
        float* __restrict__ ob = out + (size_t)(B_) * CC * HW + (ROW_) * WW + (PX0_) + QOFF; \
        _Pragma("unroll")                                                           \
        for (int it = 0; it < 4; ++it) {                                            \
            const int c = wv * 16 + it * 4 + cg;                                    \
            fx4 r;                                                                  \
            r.x = SO_[BUF][c][4 * p + 0];                                           \
            r.y = SO_[BUF][c][4 * p + 1];                                           \
            r.z = SO_[BUF][c][4 * p + 2];                                           \
            r.w = SO_[BUF][c][4 * p + 3];                                           \
            __builtin_nontemporal_store(r, reinterpret_cast<fx4*>(ob + (size_t)c * HW + 4 * p)); \
        }                                                                           \
    }

#define SAMPLE_BODY(B_, ROW_, HALF_, SO_)                                           \
    {                                                                               \
        const int l8 = t & 7;                                                       \
        const int ps = t >> 3;                                                      \
        const int px0 = (HALF_) * 128;                                              \
        const unsigned* __restrict__ xb = xt + (size_t)(B_) * HW * 32;              \
        const float2* __restrict__ pqr = pq + (size_t)(B_) * HW + (ROW_) * WW + px0;\
        const float2 prA0 = pqr[ps];                                                \
        const float2 prB0 = pqr[32 + ps];                                           \
        const float2 prA1 = pqr[64 + ps];                                           \
        const float2 prB1 = pqr[96 + ps];                                           \
        float wA00, wA01, wA10, wA11, wB00, wB01, wB10, wB11;                       \
        float uA00, uA01, uA10, uA11, uB00, uB01, uB10, uB11;                       \
        unsigned iA00, iA01, iA10, iA11, iB00, iB01, iB10, iB11;                    \
        unsigned jA00, jA01, jA10, jA11, jB00, jB01, jB10, jB11;                    \
        COORDS(prA0, wA00, wA01, wA10, wA11, iA00, iA01, iA10, iA11)                \
        COORDS(prB0, wB00, wB01, wB10, wB11, iB00, iB01, iB10, iB11)                \
        COORDS(prA1, uA00, uA01, uA10, uA11, jA00, jA01, jA10, jA11)                \
        COORDS(prB1, uB00, uB01, uB10, uB11, jB00, jB01, jB10, jB11)                \
        const uint4 vA00 = *reinterpret_cast<const uint4*>(xb + iA00);              \
        const uint4 vA01 = *reinterpret_cast<const uint4*>(xb + iA01);              \
        const uint4 vA10 = *reinterpret_cast<const uint4*>(xb + iA10);              \
        const uint4 vA11 = *reinterpret_cast<const uint4*>(xb + iA11);              \
        const uint4 vB00 = *reinterpret_cast<const uint4*>(xb + iB00);              \
        const uint4 vB01 = *reinterpret_cast<const uint4*>(xb + iB01);              \
        const uint4 vB10 = *reinterpret_cast<const uint4*>(xb + iB10);              \
        const uint4 vB11 = *reinterpret_cast<const uint4*>(xb + iB11);              \
        const uint4 yA00 = *reinterpret_cast<const uint4*>(xb + jA00);              \
        const uint4 yA01 = *reinterpret_cast<const uint4*>(xb + jA01);              \
        const uint4 yA10 = *reinterpret_cast<const uint4*>(xb + jA10);              \
        const uint4 yA11 = *reinterpret_cast<const uint4*>(xb + jA11);              \
        const uint4 yB00 = *reinterpret_cast<const uint4*>(xb + jB00);              \
        const uint4 yB01 = *reinterpret_cast<const uint4*>(xb + jB01);              \
        const uint4 yB10 = *reinterpret_cast<const uint4*>(xb + jB10);              \
        const uint4 yB11 = *reinterpret_cast<const uint4*>(xb + jB11);              \
        const int c8 = l8 * 8;                                                      \
        BLEND_STORE(SO_, 0, vA00, vA01, vA10, vA11, wA00, wA01, wA10, wA11, ps)     \
        BLEND_STORE(SO_, 0, vB00, vB01, vB10, vB11, wB00, wB01, wB10, wB11, (32 + ps)) \
        __syncthreads();                                                            \
        WRITEOUT(SO_, 0, B_, ROW_, px0, 0)                                          \
        BLEND_STORE(SO_, 1, yA00, yA01, yA10, yA11, uA00, uA01, uA10, uA11, ps)     \
        BLEND_STORE(SO_, 1, yB00, yB01, yB10, yB11, uB00, uB01, uB10, uB11, (32 + ps)) \
        __syncthreads();                                                            \
        WRITEOUT(SO_, 1, B_, ROW_, px0, 64)                                         \
    }

// ---------------- pure prep: grid = pcount*256, batches [pbase, ...) ----------------
__global__ __launch_bounds__(256) void k_prep(
    const float* __restrict__ x, const float* __restrict__ w_off, const float* __restrict__ b_off,
    unsigned* __restrict__ xt, float2* __restrict__ pq, int pbase)
{
    __shared__ unsigned s_pack[CC / 2][WW + 1];
    __shared__ float sw0[CC], sw1[CC];
    const int t   = threadIdx.x;
    const int bid = blockIdx.x;
    const int b   = pbase + (bid >> 8);
    const int row = bid & 255;
    PREP_BODY(b, row, s_pack, sw0, sw1)
}

// ---------------- pure sample: grid = scount*512, batches [sbase, ...) ----------------
__global__ __launch_bounds__(256) void k_sample4(
    const unsigned* __restrict__ xt, const float2* __restrict__ pq, float* __restrict__ out,
    int sbase)
{
    __shared__ float so[2][CC][65];
    const int t   = threadIdx.x;
    const int raw = blockIdx.x;
    const int n   = gridDim.x;
    const int lb  = (raw & 7) * (n >> 3) + (raw >> 3);   // XCD chunking (n % 8 == 0)
    const int half = lb & 1;
    const int row  = (lb >> 1) & (HH - 1);
    const int b    = sbase + (lb >> 9);
    SAMPLE_BODY(b, row, half, so)
}

// ---------------- mixed launch: period P, first R of each period are prep ----------------
// grid = pcount*256 + scount*512, P = period, R = prep blocks per period.
union MixSh {
    struct { unsigned pack[CC / 2][WW + 1]; float w0[CC], w1[CC]; } p;  // 33408 B
    float so[2][CC][65];                                                 // 33280 B
};
__global__ __launch_bounds__(256) void k_mix(
    const float* __restrict__ x, const float* __restrict__ w_off, const float* __restrict__ b_off,
    unsigned* __restrict__ xt, float2* __restrict__ pq, float* __restrict__ out,
    int pbase, int sbase, int P, int R)
{
    __shared__ MixSh sh;
    const int t   = threadIdx.x;
    const int bid = blockIdx.x;
    const int q   = bid / P;
    const int r   = bid - q * P;
    if (r < R) {
        const int pidx = q * R + r;
        const int b    = pbase + (pidx >> 8);
        const int row  = pidx & 255;
        PREP_BODY(b, row, sh.p.pack, sh.p.w0, sh.p.w1)
    } else {
        const int sidx = q * (P - R) + (r - R);
        const int half = sidx & 1;
        const int row  = (sidx >> 1) & (HH - 1);
        const int b    = sbase + (sidx >> 9);
        SAMPLE_BODY(b, row, half, sh.so)
    }
}

// ============================ FALLBACK PATH (R3, verified) ============================
__global__ __launch_bounds__(256) void k_offsets(
    const float* __restrict__ x, const float* __restrict__ w_off, const float* __restrict__ b_off,
    float2* __restrict__ pq)
{
    __shared__ float s_w0[CC];
    __shared__ float s_w1[CC];
    if (threadIdx.x < CC)          s_w0[threadIdx.x]      = w_off[threadIdx.x];
    else if (threadIdx.x < 2 * CC) s_w1[threadIdx.x - CC] = w_off[threadIdx.x];
    __syncthreads();
    const int t    = blockIdx.x * blockDim.x + threadIdx.x;
    const int pix0 = t * 4;
    const int w = pix0 & (WW - 1);
    const int h = (pix0 >> 8) & (HH - 1);
    const int b = pix0 >> 16;
    const float* __restrict__ xb = x + (size_t)b * CC * HW + h * WW + w;
    float a0[4] = {0.f, 0.f, 0.f, 0.f};
    float a1[4] = {0.f, 0.f, 0.f, 0.f};
#pragma unroll 8
    for (int c = 0; c < CC; ++c) {
        const float4 v = *reinterpret_cast<const float4*>(xb + (size_t)c * HW);
        const float w0 = s_w0[c], w1 = s_w1[c];
        a0[0] = fmaf(v.x, w0, a0[0]); a1[0] = fmaf(v.x, w1, a1[0]);
        a0[1] = fmaf(v.y, w0, a0[1]); a1[1] = fmaf(v.y, w1, a1[1]);
        a0[2] = fmaf(v.z, w0, a0[2]); a1[2] = fmaf(v.z, w1, a1[2]);
        a0[3] = fmaf(v.w, w0, a0[3]); a1[3] = fmaf(v.w, w1, a1[3]);
    }
    const float b0 = b_off[0], b1 = b_off[1];
#pragma unroll
    for (int j = 0; j < 4; ++j) {
        const float offx = tanhf(a0[j] + b0) * 0.5f;
        const float offy = tanhf(a1[j] + b1) * 0.5f;
        const float gx = -1.0f + (float)(w + j) * (2.0f / (WW - 1)) + offx;
        const float gy = -1.0f + (float)h       * (2.0f / (HH - 1)) + offy;
        pq[pix0 + j] = make_float2(((gx + 1.0f) * (float)WW - 1.0f) * 0.5f,
                                   ((gy + 1.0f) * (float)HH - 1.0f) * 0.5f);
    }
}

__global__ __launch_bounds__(256, 4) void k_sample(
    const float* __restrict__ x, const float2* __restrict__ pq, float* __restrict__ out)
{
    const int bid = blockIdx.x;
    const int c = bid & (CC - 1);
    const int b = bid >> 6;
    const float* __restrict__ xp = x   + ((size_t)b * CC + c) * HW;
    float* __restrict__       op = out + ((size_t)b * CC + c) * HW;
    const float2* __restrict__ pqb = pq + (size_t)b * HW;
    const int w = threadIdx.x;
    for (int k0 = 0; k0 < HH; k0 += 4) {
        int   i00[4], i01[4], i10[4], i11[4];
        float w00[4], w01[4], w10[4], w11[4];
#pragma unroll
        for (int j = 0; j < 4; ++j) {
            const float2 p = pqb[(k0 + j) * WW + w];
            const float x0f = floorf(p.x);
            const float y0f = floorf(p.y);
            const float wx1 = p.x - x0f;
            const float wy1 = p.y - y0f;
            const float wx0 = 1.0f - wx1;
            const float wy0 = 1.0f - wy1;
            const int x0 = (int)x0f, y0 = (int)y0f;
            const int x1 = x0 + 1,   y1 = y0 + 1;
            const bool vx0 = (unsigned)x0 < WW;
            const bool vx1 = (unsigned)x1 < WW;
            const bool vy0 = (unsigned)y0 < HH;
            const bool vy1 = (unsigned)y1 < HH;
            const int cx0 = min(max(x0, 0), WW - 1);
            const int cx1 = min(max(x1, 0), WW - 1);
            const int cy0 = min(max(y0, 0), HH - 1);
            const int cy1 = min(max(y1, 0), HH - 1);
            w00[j] = (vx0 && vy0) ? wx0 * wy0 : 0.f;
            w01[j] = (vx1 && vy0) ? wx1 * wy0 : 0.f;
            w10[j] = (vx0 && vy1) ? wx0 * wy1 : 0.f;
            w11[j] = (vx1 && vy1) ? wx1 * wy1 : 0.f;
            i00[j] = cy0 * WW + cx0;
            i01[j] = cy0 * WW + cx1;
            i10[j] = cy1 * WW + cx0;
            i11[j] = cy1 * WW + cx1;
        }
        float v00[4], v01[4], v10[4], v11[4];
#pragma unroll
        for (int j = 0; j < 4; ++j) v00[j] = xp[i00[j]];
#pragma unroll
        for (int j = 0; j < 4; ++j) v01[j] = xp[i01[j]];
#pragma unroll
        for (int j = 0; j < 4; ++j) v10[j] = xp[i10[j]];
#pragma unroll
        for (int j = 0; j < 4; ++j) v11[j] = xp[i11[j]];
#pragma unroll
        for (int j = 0; j < 4; ++j) {
            float v = w00[j] * v00[j];
            v = fmaf(w01[j], v01[j], v);
            v = fmaf(w10[j], v10[j], v);
            v = fmaf(w11[j], v11[j], v);
            __builtin_nontemporal_store(v, &op[(k0 + j) * WW + w]);
        }
    }
}

extern "C" void kernel_launch(void* const* d_in, const int* in_sizes, int n_in,
                              void* d_out, int out_size, void* d_ws, size_t ws_size,
                              hipStream_t stream) {
    const float* x     = (const float*)d_in[0];
    const float* w_off = (const float*)d_in[1];
    const float* b_off = (const float*)d_in[2];
    float* out = (float*)d_out;

    if (ws_size >= NEED_WS) {
        unsigned* xt = (unsigned*)d_ws;
        float2*   pq = (float2*)((char*)d_ws + XT_BYTES);
        // rebalanced 5-launch pipeline (edges = 2 batches each):
        // prep groups: {0,1} {2..7} {8..13} {14,15}; sample lags one launch.
        k_prep   <<< 512, 256, 0, stream>>>(x, w_off, b_off, xt, pq, 0);
        k_mix    <<<2560, 256, 0, stream>>>(x, w_off, b_off, xt, pq, out,  2,  0, 5, 3); // 6p+2s
        k_mix    <<<4608, 256, 0, stream>>>(x, w_off, b_off, xt, pq, out,  8,  2, 3, 1); // 6p+6s
        k_mix    <<<3584, 256, 0, stream>>>(x, w_off, b_off, xt, pq, out, 14,  8, 7, 1); // 2p+6s
        k_sample4<<<1024, 256, 0, stream>>>(xt, pq, out, 14);
    } else {
        float2* pq = (float2*)d_ws;
        const int grid1 = (BB * HW / 4) / 256;
        k_offsets<<<grid1, 256, 0, stream>>>(x, w_off, b_off, pq);
        k_sample<<<BB * CC, 256, 0, stream>>>(x, pq, out);
    }
}

// Round 14
// 171.821 us; speedup vs baseline: 1.0192x; 1.0192x over previous
//
#include <hip/hip_runtime.h>

// x:     [B=16, C=64, H=256, W=256] float32
// w_off: [2, 64] float32
// b_off: [2] float32
// out:   [16, 64, 256, 256] float32
#define BB 16
#define CC 64
#define HH 256
#define WW 256
#define HW (HH * WW)

// ws layout: xt bf16 [B][H][W][C] (134 MB) then pq float2 (8 MB)
#define XT_BYTES 134217728ULL
#define NEED_WS  (XT_BYTES + 8388608ULL)

typedef float    fx4 __attribute__((ext_vector_type(4)));
typedef unsigned ux4 __attribute__((ext_vector_type(4)));

__device__ __forceinline__ unsigned f2bf(float f) {
    unsigned u = __float_as_uint(f);
    u += 0x7FFFu + ((u >> 16) & 1u);          // RNE
    return u >> 16;
}
__device__ __forceinline__ float bflo(unsigned w) { return __uint_as_float(w << 16); }
__device__ __forceinline__ float bfhi(unsigned w) { return __uint_as_float(w & 0xFFFF0000u); }

// ---------------- shared-body macros (verified R12 bodies) ----------------
#define PREP_BODY(B_, ROW_, PACK_, W0_, W1_)                                        \
    {                                                                               \
        if (t < CC)          W0_[t]      = w_off[t];                                \
        else if (t < 2*CC)   W1_[t - CC] = w_off[t];                                \
        __syncthreads();                                                            \
        const float* __restrict__ xb = x + (size_t)(B_) * CC * HW + (ROW_) * WW + t;\
        float a0 = 0.f, a1 = 0.f, vprev = 0.f;                                      \
        _Pragma("unroll 16")                                                        \
        for (int c = 0; c < CC; ++c) {                                              \
            const float v = xb[(size_t)c * HW];                                     \
            a0 = fmaf(v, W0_[c], a0);                                               \
            a1 = fmaf(v, W1_[c], a1);                                               \
            if (c & 1) PACK_[c >> 1][t] = f2bf(vprev) | (f2bf(v) << 16);            \
            vprev = v;                                                              \
        }                                                                           \
        const float offx = tanhf(a0 + b_off[0]) * 0.5f;                             \
        const float offy = tanhf(a1 + b_off[1]) * 0.5f;                             \
        const float gx = -1.0f + (float)t      * (2.0f / (WW - 1)) + offx;          \
        const float gy = -1.0f + (float)(ROW_) * (2.0f / (HH - 1)) + offy;          \
        pq[(size_t)(B_) * HW + (ROW_) * WW + t] =                                   \
            make_float2(((gx + 1.0f) * (float)WW - 1.0f) * 0.5f,                    \
                        ((gy + 1.0f) * (float)HH - 1.0f) * 0.5f);                   \
        __syncthreads();                                                            \
        const int j  = t & 7;                                                       \
        const int pb = t >> 3;                                                      \
        unsigned* __restrict__ xto = xt + ((size_t)(B_) * HW + (size_t)(ROW_) * WW) * 32; \
        _Pragma("unroll")                                                           \
        for (int g = 0; g < 8; ++g) {                                               \
            const int p = g * 32 + pb;                                              \
            ux4 v;                                                                  \
            v.x = PACK_[4 * j + 0][p];                                              \
            v.y = PACK_[4 * j + 1][p];                                              \
            v.z = PACK_[4 * j + 2][p];                                              \
            v.w = PACK_[4 * j + 3][p];                                              \
            *reinterpret_cast<ux4*>(xto + (size_t)p * 32 + j * 4) = v;              \
        }                                                                           \
    }

#define COORDS(prc, W00, W01, W10, W11, I00, I01, I10, I11)                         \
    {                                                                               \
        const float x0f = floorf(prc.x), y0f = floorf(prc.y);                       \
        const float wx1 = prc.x - x0f,  wy1 = prc.y - y0f;                          \
        const float wx0 = 1.f - wx1,   wy0 = 1.f - wy1;                             \
        const int x0 = (int)x0f, y0 = (int)y0f, x1 = x0 + 1, y1 = y0 + 1;           \
        const bool vx0 = (unsigned)x0 < WW, vx1 = (unsigned)x1 < WW;                \
        const bool vy0 = (unsigned)y0 < HH, vy1 = (unsigned)y1 < HH;                \
        const int cx0 = min(max(x0, 0), WW - 1), cx1 = min(max(x1, 0), WW - 1);     \
        const int cy0 = min(max(y0, 0), HH - 1), cy1 = min(max(y1, 0), HH - 1);     \
        W00 = (vx0 && vy0) ? wx0 * wy0 : 0.f;                                       \
        W01 = (vx1 && vy0) ? wx1 * wy0 : 0.f;                                       \
        W10 = (vx0 && vy1) ? wx0 * wy1 : 0.f;                                       \
        W11 = (vx1 && vy1) ? wx1 * wy1 : 0.f;                                       \
        I00 = (unsigned)(cy0 * WW + cx0) * 32u + l8 * 4u;                           \
        I01 = (unsigned)(cy0 * WW + cx1) * 32u + l8 * 4u;                           \
        I10 = (unsigned)(cy1 * WW + cx0) * 32u + l8 * 4u;                           \
        I11 = (unsigned)(cy1 * WW + cx1) * 32u + l8 * 4u;                           \
    }

#define BLEND_STORE(SO_, BUF, V00, V01, V10, V11, W00, W01, W10, W11, PXL)          \
    {                                                                               \
        float f0 = W00 * bflo(V00.x); float f1 = W00 * bfhi(V00.x);                 \
        float f2 = W00 * bflo(V00.y); float f3 = W00 * bfhi(V00.y);                 \
        float f4 = W00 * bflo(V00.z); float f5 = W00 * bfhi(V00.z);                 \
        float f6 = W00 * bflo(V00.w); float f7 = W00 * bfhi(V00.w);                 \
        f0 = fmaf(W01, bflo(V01.x), f0); f1 = fmaf(W01, bfhi(V01.x), f1);           \
        f2 = fmaf(W01, bflo(V01.y), f2); f3 = fmaf(W01, bfhi(V01.y), f3);           \
        f4 = fmaf(W01, bflo(V01.z), f4); f5 = fmaf(W01, bfhi(V01.z), f5);           \
        f6 = fmaf(W01, bflo(V01.w), f6); f7 = fmaf(W01, bfhi(V01.w), f7);           \
        f0 = fmaf(W10, bflo(V10.x), f0); f1 = fmaf(W10, bfhi(V10.x), f1);           \
        f2 = fmaf(W10, bflo(V10.y), f2); f3 = fmaf(W10, bfhi(V10.y), f3);           \
        f4 = fmaf(W10, bflo(V10.z), f4); f5 = fmaf(W10, bfhi(V10.z), f5);           \
        f6 = fmaf(W10, bflo(V10.w), f6); f7 = fmaf(W10, bfhi(V10.w), f7);           \
        f0 = fmaf(W11, bflo(V11.x), f0); f1 = fmaf(W11, bfhi(V11.x), f1);           \
        f2 = fmaf(W11, bflo(V11.y), f2); f3 = fmaf(W11, bfhi(V11.y), f3);           \
        f4 = fmaf(W11, bflo(V11.z), f4); f5 = fmaf(W11, bfhi(V11.z), f5);           \
        f6 = fmaf(W11, bflo(V11.w), f6); f7 = fmaf(W11, bfhi(V11.w), f7);           \
        SO_[BUF][c8 + 0][PXL] = f0; SO_[BUF][c8 + 1][PXL] = f1;                     \
        SO_[BUF][c8 + 2][PXL] = f2; SO_[BUF][c8 + 3][PXL] = f3;                     \
        SO_[BUF][c8 + 4][PXL] = f4; SO_[BUF][c8 + 5][PXL] = f5;                     \
        SO_[BUF][c8 + 6][PXL] = f6; SO_[BUF][c8 + 7][PXL] = f7;                     \
    }

#define WRITEOUT(SO_, BUF, B_, ROW_, PX0_, QOFF)                                    \
    {                                                                               \
        const int p  = t & 15;                                                      \
        const int cg = (t >> 4) & 3;                                                \
        const int wv = t >> 6;                                                      \
        float* __restrict__ ob = out + (size_t)(B_) * CC * HW + (ROW_) * WW + (PX0_) + QOFF; \
        _Pragma("unroll")                                                           \
        for (int it = 0; it < 4; ++it) {                                            \
            const int c = wv * 16 + it * 4 + cg;                                    \
            fx4 r;                                                                  \
            r.x = SO_[BUF][c][4 * p + 0];                                           \
            r.y = SO_[BUF][c][4 * p + 1];                                           \
            r.z = SO_[BUF][c][4 * p + 2];                                           \
            r.w = SO_[BUF][c][4 * p + 3];                                           \
            __builtin_nontemporal_store(r, reinterpret_cast<fx4*>(ob + (size_t)c * HW + 4 * p)); \
        }                                                                           \
    }

#define SAMPLE_BODY(B_, ROW_, HALF_, SO_)                                           \
    {                                                                               \
        const int l8 = t & 7;                                                       \
        const int ps = t >> 3;                                                      \
        const int px0 = (HALF_) * 128;                                              \
        const unsigned* __restrict__ xb = xt + (size_t)(B_) * HW * 32;              \
        const float2* __restrict__ pqr = pq + (size_t)(B_) * HW + (ROW_) * WW + px0;\
        const float2 prA0 = pqr[ps];                                                \
        const float2 prB0 = pqr[32 + ps];                                           \
        const float2 prA1 = pqr[64 + ps];                                           \
        const float2 prB1 = pqr[96 + ps];                                           \
        float wA00, wA01, wA10, wA11, wB00, wB01, wB10, wB11;                       \
        float uA00, uA01, uA10, uA11, uB00, uB01, uB10, uB11;                       \
        unsigned iA00, iA01, iA10, iA11, iB00, iB01, iB10, iB11;                    \
        unsigned jA00, jA01, jA10, jA11, jB00, jB01, jB10, jB11;                    \
        COORDS(prA0, wA00, wA01, wA10, wA11, iA00, iA01, iA10, iA11)                \
        COORDS(prB0, wB00, wB01, wB10, wB11, iB00, iB01, iB10, iB11)                \
        COORDS(prA1, uA00, uA01, uA10, uA11, jA00, jA01, jA10, jA11)                \
        COORDS(prB1, uB00, uB01, uB10, uB11, jB00, jB01, jB10, jB11)                \
        const uint4 vA00 = *reinterpret_cast<const uint4*>(xb + iA00);              \
        const uint4 vA01 = *reinterpret_cast<const uint4*>(xb + iA01);              \
        const uint4 vA10 = *reinterpret_cast<const uint4*>(xb + iA10);              \
        const uint4 vA11 = *reinterpret_cast<const uint4*>(xb + iA11);              \
        const uint4 vB00 = *reinterpret_cast<const uint4*>(xb + iB00);              \
        const uint4 vB01 = *reinterpret_cast<const uint4*>(xb + iB01);              \
        const uint4 vB10 = *reinterpret_cast<const uint4*>(xb + iB10);              \
        const uint4 vB11 = *reinterpret_cast<const uint4*>(xb + iB11);              \
        const uint4 yA00 = *reinterpret_cast<const uint4*>(xb + jA00);              \
        const uint4 yA01 = *reinterpret_cast<const uint4*>(xb + jA01);              \
        const uint4 yA10 = *reinterpret_cast<const uint4*>(xb + jA10);              \
        const uint4 yA11 = *reinterpret_cast<const uint4*>(xb + jA11);              \
        const uint4 yB00 = *reinterpret_cast<const uint4*>(xb + jB00);              \
        const uint4 yB01 = *reinterpret_cast<const uint4*>(xb + jB01);              \
        const uint4 yB10 = *reinterpret_cast<const uint4*>(xb + jB10);              \
        const uint4 yB11 = *reinterpret_cast<const uint4*>(xb + jB11);              \
        const int c8 = l8 * 8;                                                      \
        BLEND_STORE(SO_, 0, vA00, vA01, vA10, vA11, wA00, wA01, wA10, wA11, ps)     \
        BLEND_STORE(SO_, 0, vB00, vB01, vB10, vB11, wB00, wB01, wB10, wB11, (32 + ps)) \
        __syncthreads();                                                            \
        WRITEOUT(SO_, 0, B_, ROW_, px0, 0)                                          \
        BLEND_STORE(SO_, 1, yA00, yA01, yA10, yA11, uA00, uA01, uA10, uA11, ps)     \
        BLEND_STORE(SO_, 1, yB00, yB01, yB10, yB11, uB00, uB01, uB10, uB11, (32 + ps)) \
        __syncthreads();                                                            \
        WRITEOUT(SO_, 1, B_, ROW_, px0, 64)                                         \
    }

// ---------------- pure prep: grid = pcount*256, batches [pbase, ...) ----------------
__global__ __launch_bounds__(256) void k_prep(
    const float* __restrict__ x, const float* __restrict__ w_off, const float* __restrict__ b_off,
    unsigned* __restrict__ xt, float2* __restrict__ pq, int pbase)
{
    __shared__ unsigned s_pack[CC / 2][WW + 1];
    __shared__ float sw0[CC], sw1[CC];
    const int t   = threadIdx.x;
    const int bid = blockIdx.x;
    const int b   = pbase + (bid >> 8);
    const int row = bid & 255;
    PREP_BODY(b, row, s_pack, sw0, sw1)
}

// ---------------- pure sample: grid = scount*512, batches [sbase, ...) ----------------
__global__ __launch_bounds__(256) void k_sample4(
    const unsigned* __restrict__ xt, const float2* __restrict__ pq, float* __restrict__ out,
    int sbase)
{
    __shared__ float so[2][CC][65];
    const int t   = threadIdx.x;
    const int raw = blockIdx.x;
    const int n   = gridDim.x;
    const int lb  = (raw & 7) * (n >> 3) + (raw >> 3);   // XCD chunking (n % 8 == 0)
    const int half = lb & 1;
    const int row  = (lb >> 1) & (HH - 1);
    const int b    = sbase + (lb >> 9);
    SAMPLE_BODY(b, row, half, so)
}

// ---------------- mixed launch: every 3rd block is prep, rest sample ----------------
// grid = 3072: 1024 prep (4 batches) + 2048 sample (4 batches), interleaved 1:2.
union MixSh {
    struct { unsigned pack[CC / 2][WW + 1]; float w0[CC], w1[CC]; } p;  // 33408 B
    float so[2][CC][65];                                                 // 33280 B
};
__global__ __launch_bounds__(256) void k_mix(
    const float* __restrict__ x, const float* __restrict__ w_off, const float* __restrict__ b_off,
    unsigned* __restrict__ xt, float2* __restrict__ pq, float* __restrict__ out,
    int pbase, int sbase)
{
    __shared__ MixSh sh;
    const int t   = threadIdx.x;
    const int bid = blockIdx.x;
    if (bid % 3 == 0) {
        const int pidx = bid / 3;            // 0..1023
        const int b    = pbase + (pidx >> 8);
        const int row  = pidx & 255;
        PREP_BODY(b, row, sh.p.pack, sh.p.w0, sh.p.w1)
    } else {
        const int sidx = (bid / 3) * 2 + (bid % 3) - 1;   // 0..2047
        const int half = sidx & 1;
        const int row  = (sidx >> 1) & (HH - 1);
        const int b    = sbase + (sidx >> 9);
        SAMPLE_BODY(b, row, half, sh.so)
    }
}

// ============================ FALLBACK PATH (R3, verified) ============================
__global__ __launch_bounds__(256) void k_offsets(
    const float* __restrict__ x, const float* __restrict__ w_off, const float* __restrict__ b_off,
    float2* __restrict__ pq)
{
    __shared__ float s_w0[CC];
    __shared__ float s_w1[CC];
    if (threadIdx.x < CC)          s_w0[threadIdx.x]      = w_off[threadIdx.x];
    else if (threadIdx.x < 2 * CC) s_w1[threadIdx.x - CC] = w_off[threadIdx.x];
    __syncthreads();
    const int t    = blockIdx.x * blockDim.x + threadIdx.x;
    const int pix0 = t * 4;
    const int w = pix0 & (WW - 1);
    const int h = (pix0 >> 8) & (HH - 1);
    const int b = pix0 >> 16;
    const float* __restrict__ xb = x + (size_t)b * CC * HW + h * WW + w;
    float a0[4] = {0.f, 0.f, 0.f, 0.f};
    float a1[4] = {0.f, 0.f, 0.f, 0.f};
#pragma unroll 8
    for (int c = 0; c < CC; ++c) {
        const float4 v = *reinterpret_cast<const float4*>(xb + (size_t)c * HW);
        const float w0 = s_w0[c], w1 = s_w1[c];
        a0[0] = fmaf(v.x, w0, a0[0]); a1[0] = fmaf(v.x, w1, a1[0]);
        a0[1] = fmaf(v.y, w0, a0[1]); a1[1] = fmaf(v.y, w1, a1[1]);
        a0[2] = fmaf(v.z, w0, a0[2]); a1[2] = fmaf(v.z, w1, a1[2]);
        a0[3] = fmaf(v.w, w0, a0[3]); a1[3] = fmaf(v.w, w1, a1[3]);
    }
    const float b0 = b_off[0], b1 = b_off[1];
#pragma unroll
    for (int j = 0; j < 4; ++j) {
        const float offx = tanhf(a0[j] + b0) * 0.5f;
        const float offy = tanhf(a1[j] + b1) * 0.5f;
        const float gx = -1.0f + (float)(w + j) * (2.0f / (WW - 1)) + offx;
        const float gy = -1.0f + (float)h       * (2.0f / (HH - 1)) + offy;
        pq[pix0 + j] = make_float2(((gx + 1.0f) * (float)WW - 1.0f) * 0.5f,
                                   ((gy + 1.0f) * (float)HH - 1.0f) * 0.5f);
    }
}

__global__ __launch_bounds__(256, 4) void k_sample(
    const float* __restrict__ x, const float2* __restrict__ pq, float* __restrict__ out)
{
    const int bid = blockIdx.x;
    const int c = bid & (CC - 1);
    const int b = bid >> 6;
    const float* __restrict__ xp = x   + ((size_t)b * CC + c) * HW;
    float* __restrict__       op = out + ((size_t)b * CC + c) * HW;
    const float2* __restrict__ pqb = pq + (size_t)b * HW;
    const int w = threadIdx.x;
    for (int k0 = 0; k0 < HH; k0 += 4) {
        int   i00[4], i01[4], i10[4], i11[4];
        float w00[4], w01[4], w10[4], w11[4];
#pragma unroll
        for (int j = 0; j < 4; ++j) {
            const float2 p = pqb[(k0 + j) * WW + w];
            const float x0f = floorf(p.x);
            const float y0f = floorf(p.y);
            const float wx1 = p.x - x0f;
            const float wy1 = p.y - y0f;
            const float wx0 = 1.0f - wx1;
            const float wy0 = 1.0f - wy1;
            const int x0 = (int)x0f, y0 = (int)y0f;
            const int x1 = x0 + 1,   y1 = y0 + 1;
            const bool vx0 = (unsigned)x0 < WW;
            const bool vx1 = (unsigned)x1 < WW;
            const bool vy0 = (unsigned)y0 < HH;
            const bool vy1 = (unsigned)y1 < HH;
            const int cx0 = min(max(x0, 0), WW - 1);
            const int cx1 = min(max(x1, 0), WW - 1);
            const int cy0 = min(max(y0, 0), HH - 1);
            const int cy1 = min(max(y1, 0), HH - 1);
            w00[j] = (vx0 && vy0) ? wx0 * wy0 : 0.f;
            w01[j] = (vx1 && vy0) ? wx1 * wy0 : 0.f;
            w10[j] = (vx0 && vy1) ? wx0 * wy1 : 0.f;
            w11[j] = (vx1 && vy1) ? wx1 * wy1 : 0.f;
            i00[j] = cy0 * WW + cx0;
            i01[j] = cy0 * WW + cx1;
            i10[j] = cy1 * WW + cx0;
            i11[j] = cy1 * WW + cx1;
        }
        float v00[4], v01[4], v10[4], v11[4];
#pragma unroll
        for (int j = 0; j < 4; ++j) v00[j] = xp[i00[j]];
#pragma unroll
        for (int j = 0; j < 4; ++j) v01[j] = xp[i01[j]];
#pragma unroll
        for (int j = 0; j < 4; ++j) v10[j] = xp[i10[j]];
#pragma unroll
        for (int j = 0; j < 4; ++j) v11[j] = xp[i11[j]];
#pragma unroll
        for (int j = 0; j < 4; ++j) {
            float v = w00[j] * v00[j];
            v = fmaf(w01[j], v01[j], v);
            v = fmaf(w10[j], v10[j], v);
            v = fmaf(w11[j], v11[j], v);
            __builtin_nontemporal_store(v, &op[(k0 + j) * WW + w]);
        }
    }
}

extern "C" void kernel_launch(void* const* d_in, const int* in_sizes, int n_in,
                              void* d_out, int out_size, void* d_ws, size_t ws_size,
                              hipStream_t stream) {
    const float* x     = (const float*)d_in[0];
    const float* w_off = (const float*)d_in[1];
    const float* b_off = (const float*)d_in[2];
    float* out = (float*)d_out;

    if (ws_size >= NEED_WS) {
        unsigned* xt = (unsigned*)d_ws;
        float2*   pq = (float2*)((char*)d_ws + XT_BYTES);
        // R12 schedule (verified session best, 172 us): uniform 4-batch groups,
        // sample lags one launch behind its producer; cacheable xt stores (L3-resident).
        k_prep   <<<1024, 256, 0, stream>>>(x, w_off, b_off, xt, pq, 0);
        k_mix    <<<3072, 256, 0, stream>>>(x, w_off, b_off, xt, pq, out,  4,  0);
        k_mix    <<<3072, 256, 0, stream>>>(x, w_off, b_off, xt, pq, out,  8,  4);
        k_mix    <<<3072, 256, 0, stream>>>(x, w_off, b_off, xt, pq, out, 12,  8);
        k_sample4<<<2048, 256, 0, stream>>>(xt, pq, out, 12);
    } else {
        float2* pq = (float2*)d_ws;
        const int grid1 = (BB * HW / 4) / 256;
        k_offsets<<<grid1, 256, 0, stream>>>(x, w_off, b_off, pq);
        k_sample<<<BB * CC, 256, 0, stream>>>(x, pq, out);
    }
}